// Round 4
// baseline (2454.496 us; speedup 1.0000x reference)
//
#include <hip/hip_runtime.h>
#include <stdint.h>

typedef short short8 __attribute__((ext_vector_type(8)));
typedef float float4v __attribute__((ext_vector_type(4)));
typedef uint32_t u32;
typedef uint64_t u64;

#define NSTEPS 512
#define SENT 0x7F7F7F7Fu

__device__ __forceinline__ unsigned short f2bf(float f) {
  unsigned u = __builtin_bit_cast(unsigned, f);
  u += 0x7fffu + ((u >> 16) & 1u);
  return (unsigned short)(u >> 16);
}

// xbf layout (A-fragment swizzled): short8[ ((l*4+g)*16 + kk)*64 + lane ]
// element (l, g, m, k):  m = lane&15, k = kk*32 + (lane>>4)*8 + j
__global__ __launch_bounds__(256) void xprep_kernel(const float* __restrict__ x,
                                                    short* __restrict__ xbf) {
  unsigned tid = blockIdx.x * 256u + threadIdx.x;   // 2,097,152 total
  unsigned lane = tid & 63u;
  unsigned kk   = (tid >> 6) & 15u;
  unsigned g    = (tid >> 10) & 3u;
  unsigned l    = tid >> 12;
  unsigned m = lane & 15u, qo = lane >> 4;
  const float* src = x + (((size_t)(g * 16u + m) * 512u + l) * 512u + kk * 32u + qo * 8u);
  float4 a  = ((const float4*)src)[0];
  float4 b2 = ((const float4*)src)[1];
  short8 v;
  v[0] = (short)f2bf(a.x);  v[1] = (short)f2bf(a.y);
  v[2] = (short)f2bf(a.z);  v[3] = (short)f2bf(a.w);
  v[4] = (short)f2bf(b2.x); v[5] = (short)f2bf(b2.y);
  v[6] = (short)f2bf(b2.z); v[7] = (short)f2bf(b2.w);
  *(short8*)(xbf + (size_t)tid * 8u) = v;
}

// ============================================================================
// Sentinel-protocol persistent kernel (primary path).
// Every step l has its OWN 64KB sbuf slot, pre-initialized to 0x7F bytes.
// Producers: relaxed/agent u32 stores (sc1 -> coherent at IF$), NO drain, NO
// flag, NO post-store barrier. Consumers: poll the data itself — a u32 is
// valid iff != 0x7F7F7F7F (bf16 0x7F7F = 3.4e38, unreachable for |short|<=1;
// each u32 is one atomic store so halves can't tear). One IF$ round trip of
// sync latency per step instead of round-3's three (ack + flag + data).
// Correctness: slot-per-step kills staleness; a block reaches step l+1 only
// after validating ALL step-l data, which data-depends on every block's
// step-(l-1) loads having completed -> no WAR on slots, no gl-LDS race.
// ============================================================================
__global__ __launch_bounds__(256, 1) void lstm_persist_sent(
    const float* __restrict__ Wfp, const float* __restrict__ bfp,
    const float* __restrict__ Wip, const float* __restrict__ bip,
    const float* __restrict__ Wop, const float* __restrict__ bop,
    const float* __restrict__ Whp, const float* __restrict__ bhp,
    const short* __restrict__ xbf,
    short* __restrict__ sbuf,        // [512][4][16kk][64lane][8] bf16
    float* __restrict__ out)         // [64][512][512] fp32
{
  __shared__ float gl[4 * 16 * 17];  // [gate][seq][h(+pad)]

  const unsigned b = blockIdx.x;
  const unsigned g = (b & 7u) >> 1;
  const unsigned c = ((b >> 3) << 1) | (b & 1u);
  const unsigned t = threadIdx.x;
  const unsigned w = t >> 6;
  const unsigned lane = t & 63u;
  const unsigned m = lane & 15u, qo = lane >> 4;

  const float* Wsrc = (w == 0) ? Wfp : (w == 1) ? Wip : (w == 2) ? Wop : Whp;
  const float* bsrc = (w == 0) ? bfp : (w == 1) ? bip : (w == 2) ? bop : bhp;

  // one-time: this wave's B-fragments (W rows c*16+[0,16)) into registers.
  // B[k][n]: n = lane&15 (gate row), k = kk*32 + qo*8 + j.
  short8 wsf[16], wnf[16];
  {
    const float* wrow = Wsrc + (size_t)(c * 16u + m) * 1024u + qo * 8u;
#pragma unroll
    for (int kk = 0; kk < 16; kk++) {
      const float* p = wrow + kk * 32;
      short8 vs, vn;
#pragma unroll
      for (int j = 0; j < 8; j++) {
        vs[j] = (short)f2bf(p[j]);          // W_short = cols [0,512)
        vn[j] = (short)f2bf(p[512 + j]);    // W_now   = cols [512,1024)
      }
      wsf[kk] = vs;
      wnf[kk] = vn;
    }
  }
  const float bias = bsrc[c * 16u + m];

  const unsigned mm = t >> 4, hh = t & 15u;
  float longv = 0.f;
  float* outp = out + (size_t)(g * 16u + mm) * (512u * 512u) + (c * 16u + hh);

  // precomputed sbuf store slot (u32 = 2 adjacent bf16), even threads only
  u32* sdst;
  {
    unsigned k   = c * 16u + hh;       // hh even for storing threads
    unsigned kk2 = k >> 5;
    unsigned lw  = ((k >> 3) & 3u) * 16u + mm;
    unsigned jj  = k & 7u;
    sdst = (u32*)sbuf + (((size_t)g * 16u + kk2) * 64u + lw) * 4u + (jj >> 1);
  }
  const size_t sslot_u32 = (size_t)4u * 16u * 64u * 4u;  // u32s per step slot

  for (int l = 0; l < NSTEPS; l++) {
    // ---- x-part: independent of peers, overlaps producers' store latency.
    const short8* xt = (const short8*)xbf + ((size_t)(l * 4 + g) * 16u) * 64u + lane;
    short8 xa[16];
#pragma unroll
    for (int kk = 0; kk < 16; kk++) xa[kk] = xt[(size_t)kk * 64u];

    float4v acc[4];
    {
      float4v bb = {bias, bias, bias, bias};
      float4v zz = {0.f, 0.f, 0.f, 0.f};
      acc[0] = bb; acc[1] = zz; acc[2] = zz; acc[3] = zz;
    }
#pragma unroll
    for (int kk = 0; kk < 16; kk++)
      acc[kk & 3] = __builtin_amdgcn_mfma_f32_16x16x32_bf16(xa[kk], wnf[kk], acc[kk & 3], 0, 0, 0);

    if (l > 0) {
      // ---- recurrent part: validate-as-you-go sentinel loads (sc1 -> IF$).
      const u64* st = (const u64*)sbuf +
                      ((size_t)((unsigned)(l - 1) * 4u + g) * 16u) * 128u +
                      (size_t)lane * 2u;
      u64 lo[16], hi[16];
#pragma unroll
      for (int kk = 0; kk < 16; kk++) {           // issue all 16 up front
        lo[kk] = __hip_atomic_load(st + (size_t)kk * 128u, __ATOMIC_RELAXED,
                                   __HIP_MEMORY_SCOPE_AGENT);
        hi[kk] = __hip_atomic_load(st + (size_t)kk * 128u + 1u, __ATOMIC_RELAXED,
                                   __HIP_MEMORY_SCOPE_AGENT);
      }
#pragma unroll
      for (int kk = 0; kk < 16; kk++) {
        long spins = 0;
        for (;;) {
          u64 a = lo[kk], b2 = hi[kk];
          bool ok = ((u32)a != SENT) && ((u32)(a >> 32) != SENT) &&
                    ((u32)b2 != SENT) && ((u32)(b2 >> 32) != SENT);
          if (__all(ok)) break;
          if (++spins > (50LL * 1000 * 1000)) break;  // bail -> wrong, not hung
          lo[kk] = __hip_atomic_load(st + (size_t)kk * 128u, __ATOMIC_RELAXED,
                                     __HIP_MEMORY_SCOPE_AGENT);
          hi[kk] = __hip_atomic_load(st + (size_t)kk * 128u + 1u, __ATOMIC_RELAXED,
                                     __HIP_MEMORY_SCOPE_AGENT);
        }
        struct { u64 a, b; } p = { lo[kk], hi[kk] };
        short8 sa = __builtin_bit_cast(short8, p);
        acc[kk & 3] = __builtin_amdgcn_mfma_f32_16x16x32_bf16(sa, wsf[kk], acc[kk & 3], 0, 0, 0);
      }
    }

    float4v tot = (acc[0] + acc[1]) + (acc[2] + acc[3]);
    // C/D layout: col = lane&15 (gate row/h), row = qo*4 + r (seq)
#pragma unroll
    for (int r = 0; r < 4; r++)
      gl[(w * 16u + qo * 4u + (unsigned)r) * 17u + m] = tot[r];
    __syncthreads();

    // ---- elementwise update (all 256 threads: 16 seq x 16 h)
    float fg = gl[(0 * 16 + mm) * 17 + hh];
    float ig = gl[(1 * 16 + mm) * 17 + hh];
    float og = gl[(2 * 16 + mm) * 17 + hh];
    float hg = gl[(3 * 16 + mm) * 17 + hh];   // no activation on h (matches ref)
    fg = 1.f / (1.f + __expf(-fg));
    ig = 1.f / (1.f + __expf(-ig));
    og = 1.f / (1.f + __expf(-og));
    longv = fg * longv + ig * hg;
    float e  = __expf(-2.f * fabsf(longv));
    float th = (1.f - e) / (1.f + e);
    th = (longv < 0.f) ? -th : th;
    float sh = og * th;

    // pack adjacent-h pair into u32; even threads store coherently. No drain,
    // no flag, no barrier — consumers validate the data itself.
    unsigned short mybf = f2bf(sh);
    float shn = __shfl_xor(sh, 1);
    if ((t & 1u) == 0u) {
      u32 val = (u32)mybf | ((u32)f2bf(shn) << 16);
      __hip_atomic_store(sdst + (size_t)l * sslot_u32, val,
                         __ATOMIC_RELAXED, __HIP_MEMORY_SCOPE_AGENT);
    }
    outp[(size_t)l * 512u] = sh;
  }
}

// ============================================================================
// Fallback (round-3 proven kernel, flags + double buffer) if ws too small.
// ============================================================================
__global__ __launch_bounds__(256, 1) void lstm_persist_flags(
    const float* __restrict__ Wfp, const float* __restrict__ bfp,
    const float* __restrict__ Wip, const float* __restrict__ bip,
    const float* __restrict__ Wop, const float* __restrict__ bop,
    const float* __restrict__ Whp, const float* __restrict__ bhp,
    const short* __restrict__ xbf,
    short* __restrict__ sbuf, u32* __restrict__ arrive,
    float* __restrict__ out)
{
  __shared__ float gl[4 * 16 * 17];
  const unsigned b = blockIdx.x;
  const unsigned g = (b & 7u) >> 1;
  const unsigned c = ((b >> 3) << 1) | (b & 1u);
  const unsigned t = threadIdx.x;
  const unsigned w = t >> 6;
  const unsigned lane = t & 63u;
  const unsigned m = lane & 15u, qo = lane >> 4;
  const float* Wsrc = (w == 0) ? Wfp : (w == 1) ? Wip : (w == 2) ? Wop : Whp;
  const float* bsrc = (w == 0) ? bfp : (w == 1) ? bip : (w == 2) ? bop : bhp;
  short8 wsf[16], wnf[16];
  {
    const float* wrow = Wsrc + (size_t)(c * 16u + m) * 1024u + qo * 8u;
#pragma unroll
    for (int kk = 0; kk < 16; kk++) {
      const float* p = wrow + kk * 32;
      short8 vs, vn;
#pragma unroll
      for (int j = 0; j < 8; j++) { vs[j] = (short)f2bf(p[j]); vn[j] = (short)f2bf(p[512 + j]); }
      wsf[kk] = vs; wnf[kk] = vn;
    }
  }
  const float bias = bsrc[c * 16u + m];
  const unsigned mm = t >> 4, hh = t & 15u;
  float longv = 0.f;
  float* outp = out + (size_t)(g * 16u + mm) * (512u * 512u) + (c * 16u + hh);
  u32* sdst;
  {
    unsigned k = c * 16u + hh, kk2 = k >> 5, lw = ((k >> 3) & 3u) * 16u + mm, jj = k & 7u;
    sdst = (u32*)sbuf + (((size_t)g * 16u + kk2) * 64u + lw) * 4u + (jj >> 1);
  }
  const size_t sslot = (size_t)4u * 16u * 64u * 4u;
  const u32* fl = arrive + g * 32u;
  for (int l = 0; l < NSTEPS; l++) {
    const short8* xt = (const short8*)xbf + ((size_t)(l * 4 + g) * 16u) * 64u + lane;
    short8 xa[16];
#pragma unroll
    for (int kk = 0; kk < 16; kk++) xa[kk] = xt[(size_t)kk * 64u];
    float4v acc[4];
    { float4v bb = {bias, bias, bias, bias}; float4v zz = {0.f, 0.f, 0.f, 0.f};
      acc[0] = bb; acc[1] = zz; acc[2] = zz; acc[3] = zz; }
#pragma unroll
    for (int kk = 0; kk < 16; kk++)
      acc[kk & 3] = __builtin_amdgcn_mfma_f32_16x16x32_bf16(xa[kk], wnf[kk], acc[kk & 3], 0, 0, 0);
    if (l > 0) {
      if (lane < 32u) {
        long spins = 0;
        while (__hip_atomic_load(fl + lane, __ATOMIC_RELAXED, __HIP_MEMORY_SCOPE_AGENT) < (u32)l) {
          __builtin_amdgcn_s_sleep(1);
          if (++spins > (100LL * 1000 * 1000)) break;
        }
      }
      const u64* st = (const u64*)sbuf +
                      ((size_t)(((unsigned)(l - 1) & 1u) * 4u + g) * 16u) * 128u + (size_t)lane * 2u;
      u64 tmp[32];
#pragma unroll
      for (int kk = 0; kk < 16; kk++) {
        tmp[2 * kk]     = __hip_atomic_load(st + (size_t)kk * 128u, __ATOMIC_RELAXED, __HIP_MEMORY_SCOPE_AGENT);
        tmp[2 * kk + 1] = __hip_atomic_load(st + (size_t)kk * 128u + 1u, __ATOMIC_RELAXED, __HIP_MEMORY_SCOPE_AGENT);
      }
#pragma unroll
      for (int kk = 0; kk < 16; kk++) {
        struct { u64 a, b; } p = { tmp[2 * kk], tmp[2 * kk + 1] };
        short8 sa = __builtin_bit_cast(short8, p);
        acc[kk & 3] = __builtin_amdgcn_mfma_f32_16x16x32_bf16(sa, wsf[kk], acc[kk & 3], 0, 0, 0);
      }
    }
    float4v tot = (acc[0] + acc[1]) + (acc[2] + acc[3]);
#pragma unroll
    for (int r = 0; r < 4; r++) gl[(w * 16u + qo * 4u + (unsigned)r) * 17u + m] = tot[r];
    __syncthreads();
    float fg = gl[(0 * 16 + mm) * 17 + hh];
    float ig = gl[(1 * 16 + mm) * 17 + hh];
    float og = gl[(2 * 16 + mm) * 17 + hh];
    float hg = gl[(3 * 16 + mm) * 17 + hh];
    fg = 1.f / (1.f + __expf(-fg));
    ig = 1.f / (1.f + __expf(-ig));
    og = 1.f / (1.f + __expf(-og));
    longv = fg * longv + ig * hg;
    float e = __expf(-2.f * fabsf(longv));
    float th = (1.f - e) / (1.f + e);
    th = (longv < 0.f) ? -th : th;
    float sh = og * th;
    unsigned short mybf = f2bf(sh);
    float shn = __shfl_xor(sh, 1);
    if ((t & 1u) == 0u) {
      u32 val = (u32)mybf | ((u32)f2bf(shn) << 16);
      __hip_atomic_store(sdst + ((size_t)((unsigned)l & 1u)) * sslot, val,
                         __ATOMIC_RELAXED, __HIP_MEMORY_SCOPE_AGENT);
    }
    __syncthreads();
    if (t == 0)
      __hip_atomic_store((u32*)(arrive + g * 32u + c), (u32)(l + 1),
                         __ATOMIC_RELAXED, __HIP_MEMORY_SCOPE_AGENT);
    outp[(size_t)l * 512u] = sh;
  }
}

extern "C" void kernel_launch(void* const* d_in, const int* in_sizes, int n_in,
                              void* d_out, int out_size, void* d_ws, size_t ws_size,
                              hipStream_t stream) {
  const float* x   = (const float*)d_in[0];
  const float* Wf  = (const float*)d_in[1];
  const float* bfv = (const float*)d_in[2];
  const float* Wi  = (const float*)d_in[3];
  const float* biv = (const float*)d_in[4];
  const float* Wo  = (const float*)d_in[5];
  const float* bov = (const float*)d_in[6];
  const float* Wh  = (const float*)d_in[7];
  const float* bhv = (const float*)d_in[8];
  float* out = (float*)d_out;

  char* ws = (char*)d_ws;
  short* xbf = (short*)ws;                                   // 32 MiB @ 0

  const size_t XBF = 33554432;
  const size_t SENT_BYTES = 33554432;                        // 512 slots x 64KB

  if (ws_size >= XBF + SENT_BYTES) {
    short* sbuf = (short*)(ws + XBF);
    hipMemsetAsync(ws + XBF, 0x7F, SENT_BYTES, stream);      // sentinel-init
    xprep_kernel<<<8192, 256, 0, stream>>>(x, xbf);
    lstm_persist_sent<<<128, 256, 0, stream>>>(Wf, bfv, Wi, biv, Wo, bov,
                                               Wh, bhv, xbf, sbuf, out);
  } else {
    short* sbuf   = (short*)(ws + XBF);                      // 128 KiB
    u32*   arrive = (u32*)(ws + XBF + 131072);               // 512 B
    hipMemsetAsync(ws + XBF + 131072, 0, 512, stream);
    xprep_kernel<<<8192, 256, 0, stream>>>(x, xbf);
    lstm_persist_flags<<<128, 256, 0, stream>>>(Wf, bfv, Wi, biv, Wo, bov,
                                                Wh, bhv, xbf, sbuf, arrive, out);
  }
}